// Round 9
// baseline (264.337 us; speedup 1.0000x reference)
//
#include <hip/hip_runtime.h>

typedef __bf16 bf16;
typedef __attribute__((ext_vector_type(4))) __bf16 bf16x4;
typedef __attribute__((ext_vector_type(8))) __bf16 bf16x8;
typedef __attribute__((ext_vector_type(4))) float f32x4;
typedef __attribute__((ext_vector_type(4))) unsigned int u32x4;

#define B_ 4
#define S_ 2048
#define D_ 1024
#define H_ 16
#define HD_ 64

#define GLB(p) ((const __attribute__((address_space(1))) void*)(p))
#define LDS(p) ((__attribute__((address_space(3))) void*)(p))

// ---------------- pass 0a: weight transpose+convert (K,N)fp32 -> (N,K)bf16 --
__global__ __launch_bounds__(256) void transpose_cvt(
    const float* __restrict__ W0, const float* __restrict__ W1,
    const float* __restrict__ W2, const float* __restrict__ W3,
    bf16* __restrict__ T0, bf16* __restrict__ T1,
    bf16* __restrict__ T2, bf16* __restrict__ T3)
{
    __shared__ float tile[32][33];
    int z = blockIdx.z;
    const float* W = (z == 0) ? W0 : (z == 1) ? W1 : (z == 2) ? W2 : W3;
    bf16*        T = (z == 0) ? T0 : (z == 1) ? T1 : (z == 2) ? T2 : T3;
    int bx = blockIdx.x * 32, by = blockIdx.y * 32;
    int tx = threadIdx.x & 31, ty = threadIdx.x >> 5;
    #pragma unroll
    for (int j = 0; j < 32; j += 8)
        tile[ty + j][tx] = W[(size_t)(by + ty + j) * D_ + bx + tx];
    __syncthreads();
    #pragma unroll
    for (int j = 0; j < 32; j += 8)
        T[(size_t)(bx + ty + j) * D_ + by + tx] = (bf16)tile[tx][ty + j];
}

// ---------------- pass 0b: X fp32 -> bf16 ----------------
__global__ __launch_bounds__(256) void cvt_x(
    const float* __restrict__ X, bf16* __restrict__ Xb)
{
    size_t i = ((size_t)blockIdx.x * 256 + threadIdx.x) * 8;
    f32x4 a = *(const f32x4*)(X + i);
    f32x4 b = *(const f32x4*)(X + i + 4);
    bf16x8 v;
    #pragma unroll
    for (int j = 0; j < 4; ++j) { v[j] = (bf16)a[j]; v[4 + j] = (bf16)b[j]; }
    *(bf16x8*)(Xb + i) = v;
}

// ---------------- pass 1: fused QKV projection GEMM (256^2 8-phase) --------
// v10: T3+T4+T5 8-phase counted-vmcnt template (m201 structure, 1563 TF@4k).
// One N=3072 GEMM (WqT/WkT/WvT contiguous in ws). 512 thr = 8 waves (2Mx4N),
// BM=BN=256, BK=64. LDS 128 KiB = 2 bufs x {A: 2x[128x64], B: 2x[128x64]}.
// Iteration = 2 K-tiles x 4 quadrant-phases. Phases 0-3 compute buf0, stage
// buf1<-kt+1 (1 half-tile = 2 global_load_lds per phase); phases 4-7 compute
// buf1, stage buf0<-kt+2 (legal: buf0 readers retired at ph3's trailing
// barrier). Counted waits ONLY at ph0/ph4: vmcnt(2) — needed 8 loads drain,
// own 2 stay in flight; vmcnt(0) only at last iteration's ph4.
// Swizzle: v8-verified 128B-row chunk^(row&7) (0 conflicts), linear DMA dest
// + pre-swizzled global source + swizzled reads (rule #21).
// XCD remap: xcd owns 4 M-tiles (A slice 2 MB -> L2-resident).
__global__ __launch_bounds__(512, 2) void qkv_gemm(
    const bf16* __restrict__ Xb, const bf16* __restrict__ WqT,
    const float* __restrict__ bq, const float* __restrict__ bk, const float* __restrict__ bv,
    bf16* __restrict__ Qo, bf16* __restrict__ Ko, bf16* __restrict__ Vo)
{
    __shared__ bf16 As[2][2][8192];   // [buf][half][128 rows x 64 cols]
    __shared__ bf16 Bs[2][2][8192];

    const int lin = blockIdx.x;
    const int xcd = lin & 7, rr = lin >> 3;
    const int byb = xcd * 4 + (rr & 3);    // M-tile 0..31
    const int bxb = rr >> 2;               // N-tile 0..11
    const int m0 = byb * 256, n0 = bxb * 256;
    const int z = bxb >> 2;                // 4 N-tiles per z

    const float* bias = (z == 0) ? bq : (z == 1) ? bk : bv;
    bf16*        out  = (z == 0) ? Qo : (z == 1) ? Ko : Vo;
    const float scale = (z == 0) ? 0.18033688011112042f : 1.0f;

    const int t = threadIdx.x;
    const int lid = t & 63, w = t >> 6;
    const int wm = w & 1, wn = w >> 1;
    const int lrow = lid & 15, quad = lid >> 4;
    const int rsw = lrow & 7;

    // staging: thread t owns chunks t and t+512 of a [128x64] half-tile.
    // chunk g: row = g>>3 (srow1 = srow0+64, same &7), col16 = (g&7)^(row&7).
    const int srow0 = t >> 3;
    const int sc0 = ((t & 7) ^ (srow0 & 7)) << 3;   // element offset in row

    const bf16* aS[2] = { Xb  + (size_t)m0 * D_,        Xb  + (size_t)(m0 + 128) * D_ };
    const bf16* bS[2] = { WqT + (size_t)n0 * D_,        WqT + (size_t)(n0 + 128) * D_ };

    auto STG = [&](bf16* dst, const bf16* src) {
        __builtin_amdgcn_global_load_lds(GLB(src + (size_t)srow0 * D_ + sc0),
                                         LDS((char*)dst + (t << 4)), 16, 0, 0);
        __builtin_amdgcn_global_load_lds(GLB(src + (size_t)(srow0 + 64) * D_ + sc0),
                                         LDS((char*)dst + (t << 4) + 8192), 16, 0, 0);
    };

    f32x4 acc[8][4] = {};

    // prologue: buf0 <- K-tile 0
    STG(As[0][0], aS[0]); STG(As[0][1], aS[1]);
    STG(Bs[0][0], bS[0]); STG(Bs[0][1], bS[1]);
    asm volatile("s_waitcnt vmcnt(0)" ::: "memory");
    asm volatile("s_barrier" ::: "memory");

    #pragma unroll 1
    for (int it = 0; it < 8; ++it) {
        const bool lastit = (it == 7);
        const int ko1 = (2 * it + 1) << 6;   // element offset of kt=2it+1
        const int ko2 = (2 * it + 2) << 6;

        bf16x8 a[4][2];      // A-frags for current qm half (reloaded per half)
        bf16x8 bfr[4][2];    // B-frags cached for the whole K-tile

        #pragma unroll
        for (int ph = 0; ph < 8; ++ph) {
            const int buf = ph >> 2;
            const int sub = ph & 3;
            const int qm = sub >> 1, qn = sub & 1;

            // ---- stage issue (1 half-tile = 2 loads) ----
            if (ph == 0) STG(As[1][0], aS[0] + ko1);
            if (ph == 1) STG(As[1][1], aS[1] + ko1);
            if (ph == 2) STG(Bs[1][0], bS[0] + ko1);
            if (ph == 3) STG(Bs[1][1], bS[1] + ko1);
            if (!lastit) {
                if (ph == 4) STG(As[0][0], aS[0] + ko2);
                if (ph == 5) STG(As[0][1], aS[1] + ko2);
                if (ph == 6) STG(Bs[0][0], bS[0] + ko2);
                if (ph == 7) STG(Bs[0][1], bS[1] + ko2);
            }

            // ---- counted waits (before reading freshly-staged buf) ----
            if (ph == 0) asm volatile("s_waitcnt vmcnt(2)" ::: "memory");
            if (ph == 4) {
                if (lastit) asm volatile("s_waitcnt vmcnt(0)" ::: "memory");
                else        asm volatile("s_waitcnt vmcnt(2)" ::: "memory");
            }
            asm volatile("s_barrier" ::: "memory");

            // ---- ds_reads (compiler inserts lgkmcnt deps before MFMA) ----
            const char* Ah = (const char*)As[buf][wm];
            const char* Bh = (const char*)Bs[buf][wn >> 1];
            if (qn == 0) {  // phases 0,2: (re)load A-frags for this qm half
                #pragma unroll
                for (int m4 = 0; m4 < 4; ++m4)
                    #pragma unroll
                    for (int ks = 0; ks < 2; ++ks)
                        a[m4][ks] = *(const bf16x8*)(Ah + (qm * 64 + m4 * 16 + lrow) * 128
                                                        + ((((ks << 2) + quad) ^ rsw) << 4));
            }
            if (sub == 0 || sub == 1) {  // load B pair nb = sub*2, sub*2+1
                #pragma unroll
                for (int n2 = 0; n2 < 2; ++n2)
                    #pragma unroll
                    for (int ks = 0; ks < 2; ++ks)
                        bfr[sub * 2 + n2][ks] = *(const bf16x8*)(Bh
                            + ((wn & 1) * 64 + (sub * 2 + n2) * 16 + lrow) * 128
                            + ((((ks << 2) + quad) ^ rsw) << 4));
            }

            // ---- 16 MFMA (one C-quadrant x K=64) ----
            __builtin_amdgcn_s_setprio(1);
            #pragma unroll
            for (int m4 = 0; m4 < 4; ++m4)
                #pragma unroll
                for (int n2 = 0; n2 < 2; ++n2) {
                    f32x4 acv = acc[qm * 4 + m4][qn * 2 + n2];
                    acv = __builtin_amdgcn_mfma_f32_16x16x32_bf16(a[m4][0], bfr[qn * 2 + n2][0], acv, 0, 0, 0);
                    acv = __builtin_amdgcn_mfma_f32_16x16x32_bf16(a[m4][1], bfr[qn * 2 + n2][1], acv, 0, 0, 0);
                    acc[qm * 4 + m4][qn * 2 + n2] = acv;
                }
            __builtin_amdgcn_s_setprio(0);
            asm volatile("s_barrier" ::: "memory");
        }
    }

    // ---- epilogue: scatter to Q/K ([b,h,s,hd]) or V^T ([b,h,hd,s]) ----
    #pragma unroll
    for (int mb = 0; mb < 8; ++mb) {
        #pragma unroll
        for (int nb = 0; nb < 4; ++nb) {
            int gn = n0 + wn * 64 + nb * 16 + lrow;
            int nz = gn & 1023;
            float bsv = bias[nz];
            int h = nz >> 6, hd = nz & 63;
            int gm0 = m0 + wm * 128 + mb * 16 + quad * 4;
            int bb = gm0 >> 11, s0 = gm0 & 2047;
            if (z == 2) {
                bf16x4 pk;
                #pragma unroll
                for (int r = 0; r < 4; ++r)
                    pk[r] = (bf16)(acc[mb][nb][r] + bsv);
                *(bf16x4*)(out + (((size_t)(bb * H_ + h)) * HD_ + hd) * S_ + s0) = pk;
            } else {
                #pragma unroll
                for (int r = 0; r < 4; ++r) {
                    float v = (acc[mb][nb][r] + bsv) * scale;
                    out[(((size_t)(bb * H_ + h)) * S_ + (s0 + r)) * HD_ + hd] = (bf16)v;
                }
            }
        }
    }
}

// ---------------- pass 2: causal flash attention (S-transposed scheme) -----
// v9 VERBATIM (verified: attn below top-5 cutoff at 256.7 total).
__global__ __launch_bounds__(256) void attn_fwd(
    const bf16* __restrict__ Q, const bf16* __restrict__ K,
    const bf16* __restrict__ Vt, bf16* __restrict__ O)
{
    __shared__ bf16 Ks[64 * 64];        // [key][hd], 128B rows, XOR-swizzled
    __shared__ bf16 Vs[64 * 64];        // [hd][key], 128B rows, XOR-swizzled
    __shared__ bf16 Ps[4][16 * 64];     // per-wave P [query][key], swizzled

    // T1 XCD-aware remap (bijective on 1024 blocks)
    const int lin = blockIdx.x + (blockIdx.y << 4);
    const int xcd = lin & 7;
    const int sl  = lin >> 3;
    const int bh  = xcd * 8 + (sl >> 4);
    const int bxp = sl & 15;

    const int t = threadIdx.x, lid = t & 63, w = t >> 6;
    const int lrow = lid & 15, quad = lid >> 4;
    const int b = bh >> 4, h = bh & 15;

    const int swz = (lrow & 7) << 4;

    const int srow0 = t >> 3, srow1 = srow0 + 32;     // srow1&7 == srow0&7
    const int k8 = (t & 7) << 3;
    const int sswz = ((t & 7) << 4) ^ ((srow0 & 7) << 4);
    char* kdst0 = (char*)Ks + srow0 * 128 + sswz;
    char* kdst1 = (char*)Ks + srow1 * 128 + sswz;
    char* vdst0 = (char*)Vs + srow0 * 128 + sswz;
    char* vdst1 = (char*)Vs + srow1 * 128 + sswz;

    bf16x8 onesv;
    #pragma unroll
    for (int j = 0; j < 8; ++j) onesv[j] = (bf16)1.0f;

    #pragma unroll 1
    for (int half = 0; half < 2; ++half) {
        const int qtile = half ? bxp : (31 - bxp);
        const int qbase = qtile * 64;

        const bf16* Qp = Q + ((size_t)bh * S_ + qbase + w * 16) * HD_;
        bf16x8 qf[2];
        #pragma unroll
        for (int ks = 0; ks < 2; ++ks)
            qf[ks] = *(const bf16x8*)(Qp + lrow * HD_ + ks * 32 + quad * 8);

        f32x4 o_acc[4] = {};
        f32x4 l_acc = {0.0f, 0.0f, 0.0f, 0.0f};
        float m_i = -3.0e4f;

        for (int kt = 0; kt <= qtile; ++kt) {
            const bf16* Kp = K  + ((size_t)bh * S_ + kt * 64) * HD_;
            const bf16* Vp = Vt + ((size_t)bh * HD_) * S_ + kt * 64;
            __syncthreads();
            u32x4 kv0 = *(const u32x4*)(Kp + (size_t)srow0 * HD_ + k8);
            u32x4 kv1 = *(const u32x4*)(Kp + (size_t)srow1 * HD_ + k8);
            u32x4 vv0 = *(const u32x4*)(Vp + (size_t)srow0 * S_ + k8);
            u32x4 vv1 = *(const u32x4*)(Vp + (size_t)srow1 * S_ + k8);
            *(u32x4*)kdst0 = kv0;
            *(u32x4*)kdst1 = kv1;
            *(u32x4*)vdst0 = vv0;
            *(u32x4*)vdst1 = vv1;
            __syncthreads();

            f32x4 sa[4] = {};
            #pragma unroll
            for (int ks = 0; ks < 2; ++ks) {
                const int ro = ((ks << 6) + (quad << 4)) ^ swz;
                #pragma unroll
                for (int nb = 0; nb < 4; ++nb) {
                    bf16x8 kf = *(const bf16x8*)((const char*)Ks + (nb * 16 + lrow) * 128 + ro);
                    sa[nb] = __builtin_amdgcn_mfma_f32_16x16x32_bf16(kf, qf[ks], sa[nb], 0, 0, 0);
                }
            }

            if (kt == qtile) {
                int q = qbase + w * 16 + lrow;
                #pragma unroll
                for (int nb = 0; nb < 4; ++nb) {
                    int key = kt * 64 + nb * 16 + quad * 4;
                    #pragma unroll
                    for (int r = 0; r < 4; ++r)
                        if (key + r > q) sa[nb][r] = -3.0e4f;
                }
            }

            float p[4][4];
            {
                #pragma unroll
                for (int nb = 0; nb < 4; ++nb)
                    #pragma unroll
                    for (int r = 0; r < 4; ++r)
                        p[nb][r] = __builtin_amdgcn_exp2f(sa[nb][r] - m_i);

                float r0 = fmaxf(fmaxf(sa[0][0], sa[0][1]), sa[0][2]);
                float r1 = fmaxf(fmaxf(sa[0][3], sa[1][0]), sa[1][1]);
                float r2 = fmaxf(fmaxf(sa[1][2], sa[1][3]), sa[2][0]);
                float r3 = fmaxf(fmaxf(sa[2][1], sa[2][2]), sa[2][3]);
                float r4 = fmaxf(fmaxf(sa[3][0], sa[3][1]), sa[3][2]);
                float rm = fmaxf(fmaxf(fmaxf(r0, r1), r2),
                                 fmaxf(fmaxf(r3, r4), sa[3][3]));

                if (!__all(rm <= m_i + 8.0f)) {
                    rm = fmaxf(rm, __shfl_xor(rm, 16));
                    rm = fmaxf(rm, __shfl_xor(rm, 32));
                    float mnew = fmaxf(m_i, rm);
                    float al = __builtin_amdgcn_exp2f(m_i - mnew);
                    m_i = mnew;
                    #pragma unroll
                    for (int nb = 0; nb < 4; ++nb)
                        #pragma unroll
                        for (int r = 0; r < 4; ++r) {
                            o_acc[nb][r] *= al;
                            p[nb][r] = __builtin_amdgcn_exp2f(sa[nb][r] - m_i);
                        }
                    #pragma unroll
                    for (int r = 0; r < 4; ++r)
                        l_acc[r] *= al;
                }
            }

            char* pw = (char*)Ps[w] + lrow * 128;
            #pragma unroll
            for (int nb = 0; nb < 4; ++nb) {
                bf16x4 pk;
                #pragma unroll
                for (int r = 0; r < 4; ++r)
                    pk[r] = (bf16)p[nb][r];
                *(bf16x4*)(pw + ((nb * 32 + quad * 8) ^ swz)) = pk;
            }
            asm volatile("s_waitcnt lgkmcnt(0)" ::: "memory");

            #pragma unroll
            for (int ks = 0; ks < 2; ++ks) {
                const int ro = ((ks << 6) + (quad << 4)) ^ swz;
                bf16x8 pf = *(const bf16x8*)(pw + ro);
                #pragma unroll
                for (int nb = 0; nb < 4; ++nb) {
                    bf16x8 vf = *(const bf16x8*)((const char*)Vs + (nb * 16 + lrow) * 128 + ro);
                    o_acc[nb] = __builtin_amdgcn_mfma_f32_16x16x32_bf16(vf, pf, o_acc[nb], 0, 0, 0);
                }
                l_acc = __builtin_amdgcn_mfma_f32_16x16x32_bf16(onesv, pf, l_acc, 0, 0, 0);
            }
        }

        {
            float inv = 1.0f / l_acc[0];
            int s = qbase + w * 16 + lrow;
            #pragma unroll
            for (int nb = 0; nb < 4; ++nb) {
                bf16x4 pk;
                #pragma unroll
                for (int r = 0; r < 4; ++r)
                    pk[r] = (bf16)(o_acc[nb][r] * inv);
                *(bf16x4*)(O + ((size_t)b * S_ + s) * D_ + h * 64 + nb * 16 + quad * 4) = pk;
            }
        }
        __syncthreads();
    }
}

// ---------------- pass 3: output projection GEMM (fp32 out) ----------------
// v8 (verified): BK=64 + swizzle + XCD remap (512 blocks).
__global__ __launch_bounds__(256) void proj_gemm(
    const bf16* __restrict__ A, const bf16* __restrict__ WpT,
    const float* __restrict__ bp, float* __restrict__ out)
{
    const int lin = blockIdx.x + (blockIdx.y << 3);
    const int xcd = lin & 7, rest = lin >> 3;
    const int byb = xcd * 8 + (rest & 7);
    const int bxb = rest >> 3;

    __shared__ bf16 As[128 * 64];
    __shared__ bf16 Bs[128 * 64];

    const int t = threadIdx.x;
    const int lid = t & 63, w = t >> 6;
    const int wm = w & 1, wn = w >> 1;
    const int lrow = lid & 15, quad = lid >> 4;
    const int m0 = byb * 128, n0 = bxb * 128;

    const bf16* Ag = A   + (size_t)m0 * D_;
    const bf16* Bg = WpT + (size_t)n0 * D_;

    const int srow = t >> 3;
    const int ssel = ((t & 7) ^ (srow & 7)) << 3;
    const int rsw = lrow & 7;

    f32x4 acc[4][4] = {};

    for (int k0 = 0; k0 < D_; k0 += 64) {
        __syncthreads();
        #pragma unroll
        for (int j = 0; j < 4; ++j) {
            __builtin_amdgcn_global_load_lds(
                GLB(Ag + (size_t)(srow + j * 32) * D_ + k0 + ssel),
                LDS((char*)As + j * 4096 + t * 16), 16, 0, 0);
            __builtin_amdgcn_global_load_lds(
                GLB(Bg + (size_t)(srow + j * 32) * D_ + k0 + ssel),
                LDS((char*)Bs + j * 4096 + t * 16), 16, 0, 0);
        }
        __syncthreads();
        #pragma unroll
        for (int kk = 0; kk < 2; ++kk) {
            const int ro = ((kk * 4 + quad) ^ rsw) << 4;
            bf16x8 a[4], b[4];
            #pragma unroll
            for (int mb = 0; mb < 4; ++mb)
                a[mb] = *(const bf16x8*)((const char*)As + (wm * 64 + mb * 16 + lrow) * 128 + ro);
            #pragma unroll
            for (int nb = 0; nb < 4; ++nb)
                b[nb] = *(const bf16x8*)((const char*)Bs + (wn * 64 + nb * 16 + lrow) * 128 + ro);
            #pragma unroll
            for (int mb = 0; mb < 4; ++mb)
                #pragma unroll
                for (int nb = 0; nb < 4; ++nb)
                    acc[mb][nb] = __builtin_amdgcn_mfma_f32_16x16x32_bf16(a[mb], b[nb], acc[mb][nb], 0, 0, 0);
        }
    }

    #pragma unroll
    for (int mb = 0; mb < 4; ++mb) {
        #pragma unroll
        for (int nb = 0; nb < 4; ++nb) {
            int gn = n0 + wn * 64 + nb * 16 + lrow;
            float bsv = bp[gn];
            #pragma unroll
            for (int r = 0; r < 4; ++r) {
                int gm = m0 + wm * 64 + mb * 16 + quad * 4 + r;
                out[(size_t)gm * D_ + gn] = acc[mb][nb][r] + bsv;
            }
        }
    }
}

// ---------------- launch ----------------
extern "C" void kernel_launch(void* const* d_in, const int* in_sizes, int n_in,
                              void* d_out, int out_size, void* d_ws, size_t ws_size,
                              hipStream_t stream)
{
    const float* x  = (const float*)d_in[0];
    const float* Wq = (const float*)d_in[1];
    const float* bq = (const float*)d_in[2];
    const float* Wk = (const float*)d_in[3];
    const float* bk = (const float*)d_in[4];
    const float* Wv = (const float*)d_in[5];
    const float* bv = (const float*)d_in[6];
    const float* Wp = (const float*)d_in[7];
    const float* bp = (const float*)d_in[8];

    bf16* ws = (bf16*)d_ws;
    const size_t WSZ = (size_t)D_ * D_;        // 1,048,576 elems
    const size_t BIG = (size_t)B_ * S_ * D_;   // 8,388,608 elems
    bf16* WqT = ws;
    bf16* WkT = WqT + WSZ;
    bf16* WvT = WkT + WSZ;
    bf16* WpT = WvT + WSZ;
    bf16* Qb  = WpT + WSZ;
    bf16* Kb  = Qb + BIG;
    bf16* Vb  = Kb + BIG;    // V^T layout [b,h,hd,s]
    bf16* Ab  = Vb + BIG;    // X(bf16) during qkv, then attention output

    transpose_cvt<<<dim3(32, 32, 4), 256, 0, stream>>>(
        Wq, Wk, Wv, Wp, WqT, WkT, WvT, WpT);

    cvt_x<<<dim3(4096), 256, 0, stream>>>(x, Ab);

    qkv_gemm<<<dim3(384), 512, 0, stream>>>(
        Ab, WqT, bq, bk, bv, Qb, Kb, Vb);

    attn_fwd<<<dim3(16, 64), 256, 0, stream>>>(Qb, Kb, Vb, Ab);

    proj_gemm<<<dim3(8, 64), 256, 0, stream>>>(Ab, WpT, bp, (float*)d_out);
}

// Round 10
// 254.317 us; speedup vs baseline: 1.0394x; 1.0394x over previous
//
#include <hip/hip_runtime.h>

typedef __bf16 bf16;
typedef __attribute__((ext_vector_type(4))) __bf16 bf16x4;
typedef __attribute__((ext_vector_type(8))) __bf16 bf16x8;
typedef __attribute__((ext_vector_type(4))) float f32x4;
typedef __attribute__((ext_vector_type(4))) unsigned int u32x4;

#define B_ 4
#define S_ 2048
#define D_ 1024
#define H_ 16
#define HD_ 64

#define GLB(p) ((const __attribute__((address_space(1))) void*)(p))
#define LDS(p) ((__attribute__((address_space(3))) void*)(p))

// ---------------- pass 0: fused prep ----------------
// z<4: weight transpose+convert (K,N)fp32 -> (N,K)bf16 (one W per z).
// z>=4: X fp32 -> bf16 (4096 linear blocks).
// Fusing removes one dispatch boundary; the two phases use complementary
// pipes (LDS-latency vs HBM streaming) and co-schedule.
__global__ __launch_bounds__(256) void prep(
    const float* __restrict__ W0, const float* __restrict__ W1,
    const float* __restrict__ W2, const float* __restrict__ W3,
    bf16* __restrict__ T0, bf16* __restrict__ T1,
    bf16* __restrict__ T2, bf16* __restrict__ T3,
    const float* __restrict__ X, bf16* __restrict__ Xb)
{
    __shared__ float tile[32][33];
    const int z = blockIdx.z;
    if (z < 4) {
        const float* W = (z == 0) ? W0 : (z == 1) ? W1 : (z == 2) ? W2 : W3;
        bf16*        T = (z == 0) ? T0 : (z == 1) ? T1 : (z == 2) ? T2 : T3;
        int bx = blockIdx.x * 32, by = blockIdx.y * 32;
        int tx = threadIdx.x & 31, ty = threadIdx.x >> 5;
        #pragma unroll
        for (int j = 0; j < 32; j += 8)
            tile[ty + j][tx] = W[(size_t)(by + ty + j) * D_ + bx + tx];
        __syncthreads();
        #pragma unroll
        for (int j = 0; j < 32; j += 8)
            T[(size_t)(bx + ty + j) * D_ + by + tx] = (bf16)tile[tx][ty + j];
    } else {
        int lin = (z - 4) * 1024 + blockIdx.y * 32 + blockIdx.x;
        size_t i = ((size_t)lin * 256 + threadIdx.x) * 8;
        f32x4 a = *(const f32x4*)(X + i);
        f32x4 b = *(const f32x4*)(X + i + 4);
        bf16x8 v;
        #pragma unroll
        for (int j = 0; j < 4; ++j) { v[j] = (bf16)a[j]; v[4 + j] = (bf16)b[j]; }
        *(bf16x8*)(Xb + i) = v;
    }
}

// ---------------- pass 1: fused QKV projection GEMM ----------------
// v8 VERBATIM (verified best: 74.5us, SQ_LDS_BANK_CONFLICT=0, FETCH 49MB).
// BK=64, XOR-swizzled 128B rows (rule #21: linear global_load_lds dest +
// inverse-swizzled source + swizzled reads), XCD remap so XCD x owns
// by in [8x,8x+8) across all z phases.
__global__ __launch_bounds__(256) void qkv_gemm(
    const bf16* __restrict__ Xb,
    const bf16* __restrict__ WqT, const bf16* __restrict__ WkT, const bf16* __restrict__ WvT,
    const float* __restrict__ bq, const float* __restrict__ bk, const float* __restrict__ bv,
    bf16* __restrict__ Qo, bf16* __restrict__ Ko, bf16* __restrict__ Vo)
{
    const int lin = blockIdx.x + (blockIdx.y << 3) + (blockIdx.z << 9);
    const int xcd = lin & 7, rest = lin >> 3;
    const int byb = xcd * 8 + (rest & 7);
    const int bxb = (rest >> 3) & 7;
    const int z   = rest >> 6;

    const bf16*  WT   = (z == 0) ? WqT : (z == 1) ? WkT : WvT;
    const float* bias = (z == 0) ? bq  : (z == 1) ? bk  : bv;
    bf16*        out  = (z == 0) ? Qo  : (z == 1) ? Ko  : Vo;
    const float scale = (z == 0) ? 0.18033688011112042f : 1.0f;

    __shared__ bf16 As[128 * 64];
    __shared__ bf16 Bs[128 * 64];

    const int t = threadIdx.x;
    const int lid = t & 63, w = t >> 6;
    const int wm = w & 1, wn = w >> 1;
    const int lrow = lid & 15, quad = lid >> 4;
    const int m0 = byb * 128, n0 = bxb * 128;

    const bf16* Ag = Xb + (size_t)m0 * D_;
    const bf16* Bg = WT + (size_t)n0 * D_;

    const int srow = t >> 3;                      // + j*32 per call
    const int ssel = ((t & 7) ^ (srow & 7)) << 3; // element offset in row

    const int rsw = lrow & 7;

    f32x4 acc[4][4] = {};

    for (int k0 = 0; k0 < D_; k0 += 64) {
        __syncthreads();
        #pragma unroll
        for (int j = 0; j < 4; ++j) {
            __builtin_amdgcn_global_load_lds(
                GLB(Ag + (size_t)(srow + j * 32) * D_ + k0 + ssel),
                LDS((char*)As + j * 4096 + t * 16), 16, 0, 0);
            __builtin_amdgcn_global_load_lds(
                GLB(Bg + (size_t)(srow + j * 32) * D_ + k0 + ssel),
                LDS((char*)Bs + j * 4096 + t * 16), 16, 0, 0);
        }
        __syncthreads();
        #pragma unroll
        for (int kk = 0; kk < 2; ++kk) {
            const int ro = ((kk * 4 + quad) ^ rsw) << 4;   // swizzled chunk
            bf16x8 a[4], b[4];
            #pragma unroll
            for (int mb = 0; mb < 4; ++mb)
                a[mb] = *(const bf16x8*)((const char*)As + (wm * 64 + mb * 16 + lrow) * 128 + ro);
            #pragma unroll
            for (int nb = 0; nb < 4; ++nb)
                b[nb] = *(const bf16x8*)((const char*)Bs + (wn * 64 + nb * 16 + lrow) * 128 + ro);
            #pragma unroll
            for (int mb = 0; mb < 4; ++mb)
                #pragma unroll
                for (int nb = 0; nb < 4; ++nb)
                    acc[mb][nb] = __builtin_amdgcn_mfma_f32_16x16x32_bf16(a[mb], b[nb], acc[mb][nb], 0, 0, 0);
        }
    }

    #pragma unroll
    for (int mb = 0; mb < 4; ++mb) {
        #pragma unroll
        for (int nb = 0; nb < 4; ++nb) {
            int gn = n0 + wn * 64 + nb * 16 + lrow;
            float bsv = bias[gn];
            int h = gn >> 6, hd = gn & 63;
            int gm0 = m0 + wm * 64 + mb * 16 + quad * 4;
            int bb = gm0 >> 11, s0 = gm0 & 2047;
            if (z == 2) {
                // V^T: [b, h, hd, s] — 4 consecutive s, packed 8B store
                bf16x4 pk;
                #pragma unroll
                for (int r = 0; r < 4; ++r)
                    pk[r] = (bf16)(acc[mb][nb][r] + bsv);
                *(bf16x4*)(out + (((size_t)(bb * H_ + h)) * HD_ + hd) * S_ + s0) = pk;
            } else {
                // Q/K: [b, h, s, hd]
                #pragma unroll
                for (int r = 0; r < 4; ++r) {
                    float v = (acc[mb][nb][r] + bsv) * scale;
                    out[(((size_t)(bb * H_ + h)) * S_ + (s0 + r)) * HD_ + hd] = (bf16)v;
                }
            }
        }
    }
}

// ---------------- pass 2: causal flash attention (S-transposed scheme) -----
// v9 VERBATIM (verified: attn below top-5 cutoff at 256.7 total).
// Speculative softmax light path + XCD remap + XOR swizzle + ones-MFMA
// row-sum + defer-max.
__global__ __launch_bounds__(256) void attn_fwd(
    const bf16* __restrict__ Q, const bf16* __restrict__ K,
    const bf16* __restrict__ Vt, bf16* __restrict__ O)
{
    __shared__ bf16 Ks[64 * 64];        // [key][hd], 128B rows, XOR-swizzled
    __shared__ bf16 Vs[64 * 64];        // [hd][key], 128B rows, XOR-swizzled
    __shared__ bf16 Ps[4][16 * 64];     // per-wave P [query][key], swizzled

    // T1 XCD-aware remap (bijective on 1024 blocks)
    const int lin = blockIdx.x + (blockIdx.y << 4);
    const int xcd = lin & 7;
    const int sl  = lin >> 3;
    const int bh  = xcd * 8 + (sl >> 4);
    const int bxp = sl & 15;

    const int t = threadIdx.x, lid = t & 63, w = t >> 6;
    const int lrow = lid & 15, quad = lid >> 4;
    const int b = bh >> 4, h = bh & 15;

    const int swz = (lrow & 7) << 4;

    const int srow0 = t >> 3, srow1 = srow0 + 32;     // srow1&7 == srow0&7
    const int k8 = (t & 7) << 3;
    const int sswz = ((t & 7) << 4) ^ ((srow0 & 7) << 4);
    char* kdst0 = (char*)Ks + srow0 * 128 + sswz;
    char* kdst1 = (char*)Ks + srow1 * 128 + sswz;
    char* vdst0 = (char*)Vs + srow0 * 128 + sswz;
    char* vdst1 = (char*)Vs + srow1 * 128 + sswz;

    bf16x8 onesv;
    #pragma unroll
    for (int j = 0; j < 8; ++j) onesv[j] = (bf16)1.0f;

    #pragma unroll 1
    for (int half = 0; half < 2; ++half) {
        const int qtile = half ? bxp : (31 - bxp);
        const int qbase = qtile * 64;

        const bf16* Qp = Q + ((size_t)bh * S_ + qbase + w * 16) * HD_;
        bf16x8 qf[2];
        #pragma unroll
        for (int ks = 0; ks < 2; ++ks)
            qf[ks] = *(const bf16x8*)(Qp + lrow * HD_ + ks * 32 + quad * 8);

        f32x4 o_acc[4] = {};
        f32x4 l_acc = {0.0f, 0.0f, 0.0f, 0.0f};
        float m_i = -3.0e4f;

        for (int kt = 0; kt <= qtile; ++kt) {
            const bf16* Kp = K  + ((size_t)bh * S_ + kt * 64) * HD_;
            const bf16* Vp = Vt + ((size_t)bh * HD_) * S_ + kt * 64;
            __syncthreads();
            u32x4 kv0 = *(const u32x4*)(Kp + (size_t)srow0 * HD_ + k8);
            u32x4 kv1 = *(const u32x4*)(Kp + (size_t)srow1 * HD_ + k8);
            u32x4 vv0 = *(const u32x4*)(Vp + (size_t)srow0 * S_ + k8);
            u32x4 vv1 = *(const u32x4*)(Vp + (size_t)srow1 * S_ + k8);
            *(u32x4*)kdst0 = kv0;
            *(u32x4*)kdst1 = kv1;
            *(u32x4*)vdst0 = vv0;
            *(u32x4*)vdst1 = vv1;
            __syncthreads();

            f32x4 sa[4] = {};
            #pragma unroll
            for (int ks = 0; ks < 2; ++ks) {
                const int ro = ((ks << 6) + (quad << 4)) ^ swz;
                #pragma unroll
                for (int nb = 0; nb < 4; ++nb) {
                    bf16x8 kf = *(const bf16x8*)((const char*)Ks + (nb * 16 + lrow) * 128 + ro);
                    sa[nb] = __builtin_amdgcn_mfma_f32_16x16x32_bf16(kf, qf[ks], sa[nb], 0, 0, 0);
                }
            }

            if (kt == qtile) {
                int q = qbase + w * 16 + lrow;
                #pragma unroll
                for (int nb = 0; nb < 4; ++nb) {
                    int key = kt * 64 + nb * 16 + quad * 4;
                    #pragma unroll
                    for (int r = 0; r < 4; ++r)
                        if (key + r > q) sa[nb][r] = -3.0e4f;
                }
            }

            // speculative softmax: p with OLD m_i issues immediately;
            // fmax tree in parallel; shuffles/rescale only on heavy path.
            float p[4][4];
            {
                #pragma unroll
                for (int nb = 0; nb < 4; ++nb)
                    #pragma unroll
                    for (int r = 0; r < 4; ++r)
                        p[nb][r] = __builtin_amdgcn_exp2f(sa[nb][r] - m_i);

                float r0 = fmaxf(fmaxf(sa[0][0], sa[0][1]), sa[0][2]);
                float r1 = fmaxf(fmaxf(sa[0][3], sa[1][0]), sa[1][1]);
                float r2 = fmaxf(fmaxf(sa[1][2], sa[1][3]), sa[2][0]);
                float r3 = fmaxf(fmaxf(sa[2][1], sa[2][2]), sa[2][3]);
                float r4 = fmaxf(fmaxf(sa[3][0], sa[3][1]), sa[3][2]);
                float rm = fmaxf(fmaxf(fmaxf(r0, r1), r2),
                                 fmaxf(fmaxf(r3, r4), sa[3][3]));

                if (!__all(rm <= m_i + 8.0f)) {
                    rm = fmaxf(rm, __shfl_xor(rm, 16));
                    rm = fmaxf(rm, __shfl_xor(rm, 32));
                    float mnew = fmaxf(m_i, rm);
                    float al = __builtin_amdgcn_exp2f(m_i - mnew);
                    m_i = mnew;
                    #pragma unroll
                    for (int nb = 0; nb < 4; ++nb)
                        #pragma unroll
                        for (int r = 0; r < 4; ++r) {
                            o_acc[nb][r] *= al;
                            p[nb][r] = __builtin_amdgcn_exp2f(sa[nb][r] - m_i);
                        }
                    #pragma unroll
                    for (int r = 0; r < 4; ++r)
                        l_acc[r] *= al;
                }
            }

            char* pw = (char*)Ps[w] + lrow * 128;
            #pragma unroll
            for (int nb = 0; nb < 4; ++nb) {
                bf16x4 pk;
                #pragma unroll
                for (int r = 0; r < 4; ++r)
                    pk[r] = (bf16)p[nb][r];
                *(bf16x4*)(pw + ((nb * 32 + quad * 8) ^ swz)) = pk;
            }
            asm volatile("s_waitcnt lgkmcnt(0)" ::: "memory");

            #pragma unroll
            for (int ks = 0; ks < 2; ++ks) {
                const int ro = ((ks << 6) + (quad << 4)) ^ swz;
                bf16x8 pf = *(const bf16x8*)(pw + ro);
                #pragma unroll
                for (int nb = 0; nb < 4; ++nb) {
                    bf16x8 vf = *(const bf16x8*)((const char*)Vs + (nb * 16 + lrow) * 128 + ro);
                    o_acc[nb] = __builtin_amdgcn_mfma_f32_16x16x32_bf16(vf, pf, o_acc[nb], 0, 0, 0);
                }
                l_acc = __builtin_amdgcn_mfma_f32_16x16x32_bf16(onesv, pf, l_acc, 0, 0, 0);
            }
        }

        {
            float inv = 1.0f / l_acc[0];
            int s = qbase + w * 16 + lrow;
            #pragma unroll
            for (int nb = 0; nb < 4; ++nb) {
                bf16x4 pk;
                #pragma unroll
                for (int r = 0; r < 4; ++r)
                    pk[r] = (bf16)(o_acc[nb][r] * inv);
                *(bf16x4*)(O + ((size_t)b * S_ + s) * D_ + h * 64 + nb * 16 + quad * 4) = pk;
            }
        }
        __syncthreads();
    }
}

// ---------------- pass 3: output projection GEMM (fp32 out) ----------------
// v8 VERBATIM: BK=64 + swizzle + XCD remap (512 blocks).
__global__ __launch_bounds__(256) void proj_gemm(
    const bf16* __restrict__ A, const bf16* __restrict__ WpT,
    const float* __restrict__ bp, float* __restrict__ out)
{
    const int lin = blockIdx.x + (blockIdx.y << 3);
    const int xcd = lin & 7, rest = lin >> 3;
    const int byb = xcd * 8 + (rest & 7);
    const int bxb = rest >> 3;

    __shared__ bf16 As[128 * 64];
    __shared__ bf16 Bs[128 * 64];

    const int t = threadIdx.x;
    const int lid = t & 63, w = t >> 6;
    const int wm = w & 1, wn = w >> 1;
    const int lrow = lid & 15, quad = lid >> 4;
    const int m0 = byb * 128, n0 = bxb * 128;

    const bf16* Ag = A   + (size_t)m0 * D_;
    const bf16* Bg = WpT + (size_t)n0 * D_;

    const int srow = t >> 3;
    const int ssel = ((t & 7) ^ (srow & 7)) << 3;
    const int rsw = lrow & 7;

    f32x4 acc[4][4] = {};

    for (int k0 = 0; k0 < D_; k0 += 64) {
        __syncthreads();
        #pragma unroll
        for (int j = 0; j < 4; ++j) {
            __builtin_amdgcn_global_load_lds(
                GLB(Ag + (size_t)(srow + j * 32) * D_ + k0 + ssel),
                LDS((char*)As + j * 4096 + t * 16), 16, 0, 0);
            __builtin_amdgcn_global_load_lds(
                GLB(Bg + (size_t)(srow + j * 32) * D_ + k0 + ssel),
                LDS((char*)Bs + j * 4096 + t * 16), 16, 0, 0);
        }
        __syncthreads();
        #pragma unroll
        for (int kk = 0; kk < 2; ++kk) {
            const int ro = ((kk * 4 + quad) ^ rsw) << 4;
            bf16x8 a[4], b[4];
            #pragma unroll
            for (int mb = 0; mb < 4; ++mb)
                a[mb] = *(const bf16x8*)((const char*)As + (wm * 64 + mb * 16 + lrow) * 128 + ro);
            #pragma unroll
            for (int nb = 0; nb < 4; ++nb)
                b[nb] = *(const bf16x8*)((const char*)Bs + (wn * 64 + nb * 16 + lrow) * 128 + ro);
            #pragma unroll
            for (int mb = 0; mb < 4; ++mb)
                #pragma unroll
                for (int nb = 0; nb < 4; ++nb)
                    acc[mb][nb] = __builtin_amdgcn_mfma_f32_16x16x32_bf16(a[mb], b[nb], acc[mb][nb], 0, 0, 0);
        }
    }

    #pragma unroll
    for (int mb = 0; mb < 4; ++mb) {
        #pragma unroll
        for (int nb = 0; nb < 4; ++nb) {
            int gn = n0 + wn * 64 + nb * 16 + lrow;
            float bsv = bp[gn];
            #pragma unroll
            for (int r = 0; r < 4; ++r) {
                int gm = m0 + wm * 64 + mb * 16 + quad * 4 + r;
                out[(size_t)gm * D_ + gn] = acc[mb][nb][r] + bsv;
            }
        }
    }
}

// ---------------- launch ----------------
extern "C" void kernel_launch(void* const* d_in, const int* in_sizes, int n_in,
                              void* d_out, int out_size, void* d_ws, size_t ws_size,
                              hipStream_t stream)
{
    const float* x  = (const float*)d_in[0];
    const float* Wq = (const float*)d_in[1];
    const float* bq = (const float*)d_in[2];
    const float* Wk = (const float*)d_in[3];
    const float* bk = (const float*)d_in[4];
    const float* Wv = (const float*)d_in[5];
    const float* bv = (const float*)d_in[6];
    const float* Wp = (const float*)d_in[7];
    const float* bp = (const float*)d_in[8];

    bf16* ws = (bf16*)d_ws;
    const size_t WSZ = (size_t)D_ * D_;        // 1,048,576 elems
    const size_t BIG = (size_t)B_ * S_ * D_;   // 8,388,608 elems
    bf16* WqT = ws;
    bf16* WkT = WqT + WSZ;
    bf16* WvT = WkT + WSZ;
    bf16* WpT = WvT + WSZ;
    bf16* Qb  = WpT + WSZ;
    bf16* Kb  = Qb + BIG;
    bf16* Vb  = Kb + BIG;    // V^T layout [b,h,hd,s]
    bf16* Ab  = Vb + BIG;    // X(bf16) during qkv, then attention output

    prep<<<dim3(32, 32, 8), 256, 0, stream>>>(
        Wq, Wk, Wv, Wp, WqT, WkT, WvT, WpT, x, Ab);

    qkv_gemm<<<dim3(8, 64, 3), 256, 0, stream>>>(
        Ab, WqT, WkT, WvT, bq, bk, bv, Qb, Kb, Vb);

    attn_fwd<<<dim3(16, 64), 256, 0, stream>>>(Qb, Kb, Vb, Ab);

    proj_gemm<<<dim3(8, 64), 256, 0, stream>>>(Ab, WpT, bp, (float*)d_out);
}